// Round 11
// baseline (892.689 us; speedup 1.0000x reference)
//
#include <hip/hip_runtime.h>
#include <hip/hip_bf16.h>

#define NNODES 16384
#define NEDGES 262144
#define IND    128
#define HD     256
#define OUTDIM 256
#define LAYERS 4
#define NHEADS 8
#define OCD    32
#define NGRAPH 64
#define NBATCH 256
#define XQSTR  1024   // combined qkv|xw row stride (shorts)

typedef __hip_bfloat16 bf16;
typedef __attribute__((ext_vector_type(8))) short bf16x8;
typedef __attribute__((ext_vector_type(4))) short s16x4;
typedef __attribute__((ext_vector_type(4))) float f32x4;

__device__ __forceinline__ short bfbits(float v) {
    bf16 h = __float2bfloat16(v);
    return *(short*)&h;
}
__device__ __forceinline__ float b2f(short s) {
    return __uint_as_float(((unsigned)(unsigned short)s) << 16);
}

// direct global->LDS DMA, 16 B/lane; lds base must be wave-uniform
__device__ __forceinline__ void gload_lds16(const short* g, short* l) {
    __builtin_amdgcn_global_load_lds(
        (const __attribute__((address_space(1))) void*)g,
        (__attribute__((address_space(3))) void*)l, 16, 0, 0);
}

// ---------------- weight prep: fp32 -> bf16 (flat and transposed) --------------
__global__ void cvt_kernel(const float* __restrict__ in, short* __restrict__ out, int n)
{
    int i = blockIdx.x * blockDim.x + threadIdx.x;
    if (i < n) out[i] = bfbits(in[i]);
}

// in [K,N] fp32 -> out [N,K] bf16; batched over blockIdx.y
__global__ void transpose_cvt_kernel(const float* __restrict__ in, short* __restrict__ out,
                                     int K, int N)
{
    int i = blockIdx.x * blockDim.x + threadIdx.x;
    if (i >= K * N) return;
    const float* ip = in + (size_t)blockIdx.y * K * N;
    short* op = out + (size_t)blockIdx.y * K * N;
    int k = i / N, n = i % N;
    op[(size_t)n * K + k] = bfbits(ip[i]);
}

// combined [1024,256] weight per layer: rows 0..767 = inw (as-is), 768..1023 = wg^T
__global__ void build_wcomb_kernel(const float* __restrict__ inw, const float* __restrict__ wg,
                                   short* __restrict__ wcomb)
{
    int i = blockIdx.x * blockDim.x + threadIdx.x;   // < LAYERS*1024*256
    int l = i >> 18, r = (i >> 8) & 1023, k = i & 255;
    float v;
    if (r < 768) v = inw[(size_t)l * 768 * 256 + r * 256 + k];
    else         v = wg[(size_t)l * 256 * 256 + k * 256 + (r - 768)];
    wcomb[i] = bfbits(v);
}

// combined bias [1024] per layer: 0..767 = inb, 768..1023 = 0
__global__ void build_cbias_kernel(const float* __restrict__ inb, float* __restrict__ cbias)
{
    int i = blockIdx.x * blockDim.x + threadIdx.x;   // < LAYERS*1024
    int l = i >> 10, c = i & 1023;
    cbias[i] = (c < 768) ? inb[l * 768 + c] : 0.f;
}

// ---------------- CSR build: histogram -> scan -> scatter ----------------------
__global__ void hist_kernel(const int* __restrict__ dst, int* __restrict__ cnt)
{
    int e = blockIdx.x * blockDim.x + threadIdx.x;
    if (e < NEDGES) atomicAdd(&cnt[dst[e]], 1);
}

__global__ void scan_kernel(const int* __restrict__ cnt, int* __restrict__ row_ptr)
{
    __shared__ int part[256];
    int t = threadIdx.x;
    const int PER = NNODES / 256;
    int base = t * PER;
    int s = 0;
    for (int i = 0; i < PER; i++) s += cnt[base + i];
    part[t] = s;
    __syncthreads();
    for (int off = 1; off < 256; off <<= 1) {
        int v = (t >= off) ? part[t - off] : 0;
        __syncthreads();
        part[t] += v;
        __syncthreads();
    }
    int run = (t == 0) ? 0 : part[t - 1];
    for (int i = 0; i < PER; i++) { row_ptr[base + i] = run; run += cnt[base + i]; }
    if (t == 255) row_ptr[NNODES] = run;
}

__global__ void scatter_kernel(const int* __restrict__ src, const int* __restrict__ dst,
                               const int* __restrict__ row_ptr, int* __restrict__ fill,
                               int* __restrict__ srcs)
{
    int e = blockIdx.x * blockDim.x + threadIdx.x;
    if (e >= NEDGES) return;
    int d = dst[e];
    int pos = row_ptr[d] + atomicAdd(&fill[d], 1);
    srcs[pos] = src[e];
}

// ---------------- GAT per-node attention scores (bf16 xw, stride XQSTR) --------
__global__ void gat_scores_kernel(const short* __restrict__ xw16,
                                  const float* __restrict__ asrc, const float* __restrict__ adst,
                                  float* __restrict__ ssrc, float* __restrict__ sdst)
{
    int i = blockIdx.x * blockDim.x + threadIdx.x;   // n*NHEADS + h
    if (i >= NNODES * NHEADS) return;
    int n = i >> 3, h = i & 7;
    const bf16x8* xr = (const bf16x8*)(xw16 + (size_t)n * XQSTR + h * OCD);
    float s1 = 0.f, s2 = 0.f;
#pragma unroll
    for (int g = 0; g < 4; g++) {
        bf16x8 v8 = xr[g];
#pragma unroll
        for (int j = 0; j < 8; j++) {
            float v = b2f(v8[j]);
            int d = g * 8 + j;
            s1 += v * asrc[h * OCD + d];
            s2 += v * adst[h * OCD + d];
        }
    }
    ssrc[i] = s1;
    sdst[i] = s2;
}

// ---------------- fused GAT softmax + aggregation + LayerNorm ------------------
// Wave-per-node: 4 channels/lane, 8 B row-gathers, no barriers; shuffle LN.
__global__ __launch_bounds__(256)
void gat_agg_ln_kernel(const int* __restrict__ row_ptr, const int* __restrict__ srcs,
                       const float* __restrict__ ssrc, const float* __restrict__ sdst,
                       const short* __restrict__ xw16, const float* __restrict__ xcur,
                       const float* __restrict__ colbias, const float* __restrict__ gamma,
                       const float* __restrict__ beta, float* __restrict__ out)
{
    int wave = threadIdx.x >> 6, lane = threadIdx.x & 63;
    int n = blockIdx.x * 4 + wave;
    int c0 = lane << 2;            // 4 channels per lane
    int h = c0 >> 5;               // head of all 4 channels
    int start = row_ptr[n];
    int deg = row_ptr[n + 1] - start;
    float sd = sdst[n * NHEADS + h];

    float ax = 0.f, ay = 0.f, az = 0.f, aw = 0.f, l = 0.f;
    int j = 0;
    for (; j + 4 <= deg; j += 4) {
        int e0 = srcs[start + j + 0], e1 = srcs[start + j + 1];
        int e2 = srcs[start + j + 2], e3 = srcs[start + j + 3];
        s16x4 r0 = *(const s16x4*)&xw16[(size_t)e0 * XQSTR + c0];
        s16x4 r1 = *(const s16x4*)&xw16[(size_t)e1 * XQSTR + c0];
        s16x4 r2 = *(const s16x4*)&xw16[(size_t)e2 * XQSTR + c0];
        s16x4 r3 = *(const s16x4*)&xw16[(size_t)e3 * XQSTR + c0];
        float a0 = ssrc[e0 * NHEADS + h] + sd; a0 = a0 > 0.f ? a0 : 0.2f * a0;
        float a1 = ssrc[e1 * NHEADS + h] + sd; a1 = a1 > 0.f ? a1 : 0.2f * a1;
        float a2 = ssrc[e2 * NHEADS + h] + sd; a2 = a2 > 0.f ? a2 : 0.2f * a2;
        float a3 = ssrc[e3 * NHEADS + h] + sd; a3 = a3 > 0.f ? a3 : 0.2f * a3;
        float p0 = __expf(a0), p1 = __expf(a1), p2 = __expf(a2), p3 = __expf(a3);
        l += (p0 + p1) + (p2 + p3);
        ax += p0 * b2f(r0[0]) + p1 * b2f(r1[0]) + p2 * b2f(r2[0]) + p3 * b2f(r3[0]);
        ay += p0 * b2f(r0[1]) + p1 * b2f(r1[1]) + p2 * b2f(r2[1]) + p3 * b2f(r3[1]);
        az += p0 * b2f(r0[2]) + p1 * b2f(r1[2]) + p2 * b2f(r2[2]) + p3 * b2f(r3[2]);
        aw += p0 * b2f(r0[3]) + p1 * b2f(r1[3]) + p2 * b2f(r2[3]) + p3 * b2f(r3[3]);
    }
    for (; j < deg; j++) {
        int e0 = srcs[start + j];
        s16x4 r0 = *(const s16x4*)&xw16[(size_t)e0 * XQSTR + c0];
        float a0 = ssrc[e0 * NHEADS + h] + sd; a0 = a0 > 0.f ? a0 : 0.2f * a0;
        float p0 = __expf(a0);
        l += p0;
        ax += p0 * b2f(r0[0]); ay += p0 * b2f(r0[1]);
        az += p0 * b2f(r0[2]); aw += p0 * b2f(r0[3]);
    }
    float invl = deg ? 1.f / l : 0.f;
    size_t base = (size_t)n * HD + c0;
    float4 x4 = *(const float4*)&xcur[base];
    float4 cb = *(const float4*)&colbias[c0];
    float4 v;
    v.x = ax * invl + x4.x + cb.x;
    v.y = ay * invl + x4.y + cb.y;
    v.z = az * invl + x4.z + cb.z;
    v.w = aw * invl + x4.w + cb.w;
    float s = v.x + v.y + v.z + v.w;
    float q = v.x * v.x + v.y * v.y + v.z * v.z + v.w * v.w;
#pragma unroll
    for (int off = 1; off < 64; off <<= 1) {
        s += __shfl_xor(s, off);
        q += __shfl_xor(q, off);
    }
    float mean = s * (1.f / HD);
    float var  = fmaxf(q * (1.f / HD) - mean * mean, 0.f);
    float inv  = rsqrtf(var + 1e-5f);
    float4 g  = *(const float4*)&gamma[c0];
    float4 bt = *(const float4*)&beta[c0];
    float4 y;
    y.x = (v.x - mean) * inv * g.x + bt.x;
    y.y = (v.y - mean) * inv * g.y + bt.y;
    y.z = (v.z - mean) * inv * g.z + bt.z;
    y.w = (v.w - mean) * inv * g.w + bt.w;
    *(float4*)&out[base] = y;
}

// ---------------- bf16 MFMA GEMM: C = A @ B^T (+bias)(+resid)(relu) ------------
// SWAPPED-operand mfma: mfma(bF, aF) puts lane l16 on the ROW and quad*4+r on
// 4 CONSECUTIVE COLUMNS -> float4 / s16x4 vectorized epilogue.
#define GBM 128
#define GBK 32

template<int TN>
__global__ __launch_bounds__(256)
void gemm_mfma_kernel(const short* __restrict__ A16, const short* __restrict__ B16,
                      const float* __restrict__ bias, const float* __restrict__ resid,
                      float* __restrict__ Cf, short* __restrict__ C16,
                      int M, int Nc, int K, int relu)
{
    constexpr int NTF = TN / 32;          // n-frags per wave
    __shared__ short As[GBM * GBK];       // 8 KB
    __shared__ short Bs[TN * GBK];        // 4 or 8 KB
    int tid = threadIdx.x;
    int wid = tid >> 6, lane = tid & 63;
    int quad = lane >> 4, l16 = lane & 15;
    int wm = wid >> 1, wn = wid & 1;
    int rowBase = blockIdx.y * GBM;
    int colBase = blockIdx.x * TN;

    f32x4 acc[4][NTF];
#pragma unroll
    for (int mt = 0; mt < 4; mt++)
#pragma unroll
        for (int nt = 0; nt < NTF; nt++) acc[mt][nt] = (f32x4)(0.f);

    int ar  = tid >> 2;          // 0..63
    int akq = (tid & 3) * 8;     // 0,8,16,24 (shorts)

    const short* Ag0 = &A16[(size_t)(rowBase + ar) * K + akq];
    const short* Ag1 = &A16[(size_t)(rowBase + ar + 64) * K + akq];
    const short* Bg0 = &B16[(size_t)(colBase + ar) * K + akq];
    const short* Bg1 = (TN == 128) ? &B16[(size_t)(colBase + ar + 64) * K + akq] : nullptr;
    short* AsW0 = As + wid * 512;                 // wave-uniform LDS bases (shorts)
    short* AsW1 = As + 64 * GBK + wid * 512;
    short* BsW0 = Bs + wid * 512;
    short* BsW1 = Bs + 64 * GBK + wid * 512;

    for (int k0 = 0; k0 < K; k0 += GBK) {
        gload_lds16(Ag0 + k0, AsW0);
        gload_lds16(Ag1 + k0, AsW1);
        gload_lds16(Bg0 + k0, BsW0);
        if (TN == 128) gload_lds16(Bg1 + k0, BsW1);
        __syncthreads();
        bf16x8 aF[4], bF[NTF];
#pragma unroll
        for (int mt = 0; mt < 4; mt++)
            aF[mt] = *(bf16x8*)&As[(wm * 64 + mt * 16 + l16) * GBK + quad * 8];
#pragma unroll
        for (int nt = 0; nt < NTF; nt++)
            bF[nt] = *(bf16x8*)&Bs[(wn * (TN / 2) + nt * 16 + l16) * GBK + quad * 8];
#pragma unroll
        for (int mt = 0; mt < 4; mt++)
#pragma unroll
            for (int nt = 0; nt < NTF; nt++)
                acc[mt][nt] = __builtin_amdgcn_mfma_f32_16x16x32_bf16(
                    bF[nt], aF[mt], acc[mt][nt], 0, 0, 0);   // swapped operands
        __syncthreads();
    }

    // epilogue: row = ...+l16, cols = ...+quad*4+{0..3} (contiguous)
#pragma unroll
    for (int mt = 0; mt < 4; mt++) {
        int row = rowBase + wm * 64 + mt * 16 + l16;
#pragma unroll
        for (int nt = 0; nt < NTF; nt++) {
            int col0 = colBase + wn * (TN / 2) + nt * 16 + quad * 4;
            f32x4 v = acc[mt][nt];
            if (bias) {
                float4 b4 = *(const float4*)&bias[col0];
                v[0] += b4.x; v[1] += b4.y; v[2] += b4.z; v[3] += b4.w;
            }
            if (resid) {
                float4 r4 = *(const float4*)&resid[(size_t)row * Nc + col0];
                v[0] += r4.x; v[1] += r4.y; v[2] += r4.z; v[3] += r4.w;
            }
            if (relu) {
                v[0] = fmaxf(v[0], 0.f); v[1] = fmaxf(v[1], 0.f);
                v[2] = fmaxf(v[2], 0.f); v[3] = fmaxf(v[3], 0.f);
            }
            if (Cf) {
                float4 o; o.x = v[0]; o.y = v[1]; o.z = v[2]; o.w = v[3];
                *(float4*)&Cf[(size_t)row * Nc + col0] = o;
            }
            if (C16) {
                s16x4 o;
                o[0] = bfbits(v[0]); o[1] = bfbits(v[1]);
                o[2] = bfbits(v[2]); o[3] = bfbits(v[3]);
                *(s16x4*)&C16[(size_t)row * Nc + col0] = o;
            }
        }
    }
}

// ---------------- fused GEMM + residual + LayerNorm (+postadd) -----------------
// Nc=256 fixed, TN=256 (full row per block). y = LN(A@B^T + bias + resid)*g+b
// (+postadd); writes fp32 + bf16. Row sums: quad-shuffle + cross-wave LDS.
__global__ __launch_bounds__(256)
void gemm_ln_kernel(const short* __restrict__ A16, const short* __restrict__ B16,
                    const float* __restrict__ bias, const float* __restrict__ resid,
                    const float* __restrict__ gamma, const float* __restrict__ beta,
                    const float* __restrict__ postadd,
                    float* __restrict__ outf, short* __restrict__ out16, int K)
{
    __shared__ short As[GBM * GBK];       // 8 KB
    __shared__ short Bs[256 * GBK];       // 16 KB
    __shared__ float sred_s[2][GBM];      // per-wn row partial sums
    __shared__ float sred_q[2][GBM];
    int tid = threadIdx.x;
    int wid = tid >> 6, lane = tid & 63;
    int quad = lane >> 4, l16 = lane & 15;
    int wm = wid >> 1, wn = wid & 1;
    int rowBase = blockIdx.y * GBM;

    f32x4 acc[4][8];
#pragma unroll
    for (int mt = 0; mt < 4; mt++)
#pragma unroll
        for (int nt = 0; nt < 8; nt++) acc[mt][nt] = (f32x4)(0.f);

    int ar  = tid >> 2;
    int akq = (tid & 3) * 8;

    const short* Ag0 = &A16[(size_t)(rowBase + ar) * K + akq];
    const short* Ag1 = &A16[(size_t)(rowBase + ar + 64) * K + akq];
    const short* Bg0 = &B16[(size_t)(ar) * K + akq];
    const short* Bg1 = &B16[(size_t)(ar + 64) * K + akq];
    const short* Bg2 = &B16[(size_t)(ar + 128) * K + akq];
    const short* Bg3 = &B16[(size_t)(ar + 192) * K + akq];
    short* AsW0 = As + wid * 512;
    short* AsW1 = As + 64 * GBK + wid * 512;
    short* BsW0 = Bs + wid * 512;
    short* BsW1 = Bs + 64 * GBK + wid * 512;
    short* BsW2 = Bs + 128 * GBK + wid * 512;
    short* BsW3 = Bs + 192 * GBK + wid * 512;

    for (int k0 = 0; k0 < K; k0 += GBK) {
        gload_lds16(Ag0 + k0, AsW0);
        gload_lds16(Ag1 + k0, AsW1);
        gload_lds16(Bg0 + k0, BsW0);
        gload_lds16(Bg1 + k0, BsW1);
        gload_lds16(Bg2 + k0, BsW2);
        gload_lds16(Bg3 + k0, BsW3);
        __syncthreads();
        bf16x8 aF[4], bF[8];
#pragma unroll
        for (int mt = 0; mt < 4; mt++)
            aF[mt] = *(bf16x8*)&As[(wm * 64 + mt * 16 + l16) * GBK + quad * 8];
#pragma unroll
        for (int nt = 0; nt < 8; nt++)
            bF[nt] = *(bf16x8*)&Bs[(wn * 128 + nt * 16 + l16) * GBK + quad * 8];
#pragma unroll
        for (int mt = 0; mt < 4; mt++)
#pragma unroll
            for (int nt = 0; nt < 8; nt++)
                acc[mt][nt] = __builtin_amdgcn_mfma_f32_16x16x32_bf16(
                    bF[nt], aF[mt], acc[mt][nt], 0, 0, 0);   // swapped operands
        __syncthreads();
    }

    // v = C + bias + resid (in place); accumulate row partial sums
#pragma unroll
    for (int mt = 0; mt < 4; mt++) {
        int row = rowBase + wm * 64 + mt * 16 + l16;
        float s = 0.f, q = 0.f;
#pragma unroll
        for (int nt = 0; nt < 8; nt++) {
            int col0 = wn * 128 + nt * 16 + quad * 4;
            f32x4 v = acc[mt][nt];
            float4 b4 = *(const float4*)&bias[col0];
            float4 r4 = *(const float4*)&resid[(size_t)row * HD + col0];
            v[0] += b4.x + r4.x; v[1] += b4.y + r4.y;
            v[2] += b4.z + r4.z; v[3] += b4.w + r4.w;
            acc[mt][nt] = v;
            s += (v[0] + v[1]) + (v[2] + v[3]);
            q += (v[0] * v[0] + v[1] * v[1]) + (v[2] * v[2] + v[3] * v[3]);
        }
        // reduce over the 4 quads holding this row's cols (lanes l16, +16, +32, +48)
        s += __shfl_xor(s, 16); s += __shfl_xor(s, 32);
        q += __shfl_xor(q, 16); q += __shfl_xor(q, 32);
        if (quad == 0) {
            sred_s[wn][wm * 64 + mt * 16 + l16] = s;
            sred_q[wn][wm * 64 + mt * 16 + l16] = q;
        }
    }
    __syncthreads();
    // normalize + store
#pragma unroll
    for (int mt = 0; mt < 4; mt++) {
        int rowl = wm * 64 + mt * 16 + l16;
        int row = rowBase + rowl;
        float s = sred_s[0][rowl] + sred_s[1][rowl];
        float q = sred_q[0][rowl] + sred_q[1][rowl];
        float mean = s * (1.f / HD);
        float var  = fmaxf(q * (1.f / HD) - mean * mean, 0.f);
        float inv  = rsqrtf(var + 1e-5f);
#pragma unroll
        for (int nt = 0; nt < 8; nt++) {
            int col0 = wn * 128 + nt * 16 + quad * 4;
            f32x4 v = acc[mt][nt];
            float4 g4 = *(const float4*)&gamma[col0];
            float4 bt = *(const float4*)&beta[col0];
            float4 y;
            y.x = (v[0] - mean) * inv * g4.x + bt.x;
            y.y = (v[1] - mean) * inv * g4.y + bt.y;
            y.z = (v[2] - mean) * inv * g4.z + bt.z;
            y.w = (v[3] - mean) * inv * g4.w + bt.w;
            if (postadd) {
                float4 p4 = *(const float4*)&postadd[(size_t)row * HD + col0];
                y.x += p4.x; y.y += p4.y; y.z += p4.z; y.w += p4.w;
            }
            *(float4*)&outf[(size_t)row * HD + col0] = y;
            s16x4 o;
            o[0] = bfbits(y.x); o[1] = bfbits(y.y); o[2] = bfbits(y.z); o[3] = bfbits(y.w);
            *(s16x4*)&out16[(size_t)row * HD + col0] = o;
        }
    }
}

// ---------------- LayerNorm: wave-per-row, float4, shuffle-only ----------------
__global__ __launch_bounds__(256)
void ln4_kernel(const float* __restrict__ in, const float* __restrict__ res,
                const float* __restrict__ gamma, const float* __restrict__ beta,
                const float* __restrict__ postadd,
                float* __restrict__ outf, short* __restrict__ out16)
{
    int wave = threadIdx.x >> 6, lane = threadIdx.x & 63;
    int row = blockIdx.x * 4 + wave;
    size_t base = (size_t)row * HD + lane * 4;
    float4 v = *(const float4*)&in[base];
    if (res) {
        float4 r = *(const float4*)&res[base];
        v.x += r.x; v.y += r.y; v.z += r.z; v.w += r.w;
    }
    float s = v.x + v.y + v.z + v.w;
    float q = v.x * v.x + v.y * v.y + v.z * v.z + v.w * v.w;
#pragma unroll
    for (int off = 1; off < 64; off <<= 1) {
        s += __shfl_xor(s, off);
        q += __shfl_xor(q, off);
    }
    float mean = s * (1.f / HD);
    float var  = fmaxf(q * (1.f / HD) - mean * mean, 0.f);
    float inv  = rsqrtf(var + 1e-5f);
    float4 g  = *(const float4*)&gamma[lane * 4];
    float4 bt = *(const float4*)&beta[lane * 4];
    float4 y;
    y.x = (v.x - mean) * inv * g.x + bt.x;
    y.y = (v.y - mean) * inv * g.y + bt.y;
    y.z = (v.z - mean) * inv * g.z + bt.z;
    y.w = (v.w - mean) * inv * g.w + bt.w;
    if (postadd) {
        float4 p = *(const float4*)&postadd[base];
        y.x += p.x; y.y += p.y; y.z += p.z; y.w += p.w;
    }
    if (outf) *(float4*)&outf[base] = y;
    if (out16) {
        s16x4 o;
        o[0] = bfbits(y.x); o[1] = bfbits(y.y); o[2] = bfbits(y.z); o[3] = bfbits(y.w);
        *(s16x4*)&out16[base] = o;
    }
}

// ---------------- MFMA per-graph MHA (qkv stride XQSTR) ------------------------
#define PSTR 72                       // P/VT row stride in shorts: 2-way bank alias only
__global__ __launch_bounds__(256)
void mha_mfma_kernel(const short* __restrict__ qkv16, short* __restrict__ o16)
{
    __shared__ short smem[4 * 64 * PSTR + 32 * PSTR];   // P (4w x 64q x 64k) + V^T (32d x 64k)
    short* VT = smem + 4 * 64 * PSTR;

    int b = blockIdx.x, h = blockIdx.y;
    int tid = threadIdx.x;
    int wid = tid >> 6, lane = tid & 63;
    int quad = lane >> 4, l16 = lane & 15;
    int base = b * NBATCH;
    int qrow0 = wid * 64;
    short* Pme = smem + wid * 64 * PSTR;

    const float scale2 = 0.17677669529663687f * 1.4426950408889634f; // 1/sqrt(32)*log2(e)

    bf16x8 qA[4];
#pragma unroll
    for (int mt = 0; mt < 4; mt++)
        qA[mt] = *(const bf16x8*)&qkv16[(size_t)(base + qrow0 + mt * 16 + l16) * XQSTR + h * 32 + quad * 8];

    f32x4 accO[4][2];
#pragma unroll
    for (int mt = 0; mt < 4; mt++)
#pragma unroll
        for (int dt = 0; dt < 2; dt++) accO[mt][dt] = (f32x4)(0.f);
    float lsum[4][4];
#pragma unroll
    for (int mt = 0; mt < 4; mt++)
#pragma unroll
        for (int r = 0; r < 4; r++) lsum[mt][r] = 0.f;

    for (int c = 0; c < 4; c++) {                  // 4 key-chunks of 64
        __syncthreads();
        {
            int key = tid >> 2, dq = (tid & 3) * 8;
            bf16x8 v = *(const bf16x8*)&qkv16[(size_t)(base + c * 64 + key) * XQSTR + 512 + h * 32 + dq];
#pragma unroll
            for (int j = 0; j < 8; j++) VT[(dq + j) * PSTR + key] = v[j];
        }
        __syncthreads();
        bf16x8 kB[4];
#pragma unroll
        for (int kt = 0; kt < 4; kt++)
            kB[kt] = *(const bf16x8*)&qkv16[(size_t)(base + c * 64 + kt * 16 + l16) * XQSTR + 256 + h * 32 + quad * 8];
#pragma unroll
        for (int mt = 0; mt < 4; mt++) {
#pragma unroll
            for (int kt = 0; kt < 4; kt++) {
                f32x4 s = __builtin_amdgcn_mfma_f32_16x16x32_bf16(qA[mt], kB[kt], (f32x4)(0.f), 0, 0, 0);
#pragma unroll
                for (int r = 0; r < 4; r++) {
                    float p = exp2f(s[r] * scale2);
                    lsum[mt][r] += p;
                    Pme[(mt * 16 + quad * 4 + r) * PSTR + kt * 16 + l16] = bfbits(p);
                }
            }
        }
        __syncthreads();
#pragma unroll
        for (int mt = 0; mt < 4; mt++) {
#pragma unroll
            for (int ks = 0; ks < 2; ks++) {
                bf16x8 pA = *(bf16x8*)&Pme[(mt * 16 + l16) * PSTR + ks * 32 + quad * 8];
#pragma unroll
                for (int dt = 0; dt < 2; dt++) {
                    bf16x8 vB = *(bf16x8*)&VT[(dt * 16 + l16) * PSTR + ks * 32 + quad * 8];
                    accO[mt][dt] = __builtin_amdgcn_mfma_f32_16x16x32_bf16(pA, vB, accO[mt][dt], 0, 0, 0);
                }
            }
        }
    }
#pragma unroll
    for (int mt = 0; mt < 4; mt++)
#pragma unroll
        for (int r = 0; r < 4; r++) {
            float v = lsum[mt][r];
            v += __shfl_xor(v, 1);
            v += __shfl_xor(v, 2);
            v += __shfl_xor(v, 4);
            v += __shfl_xor(v, 8);
            lsum[mt][r] = v;
        }
#pragma unroll
    for (int mt = 0; mt < 4; mt++)
#pragma unroll
        for (int dt = 0; dt < 2; dt++)
#pragma unroll
            for (int r = 0; r < 4; r++) {
                int row = base + qrow0 + mt * 16 + quad * 4 + r;
                int col = h * 32 + dt * 16 + l16;
                o16[(size_t)row * HD + col] = bfbits(accO[mt][dt][r] / lsum[mt][r]);
            }
}

// ------------------------------------------------------------------------------
extern "C" void kernel_launch(void* const* d_in, const int* in_sizes, int n_in,
                              void* d_out, int out_size, void* d_ws, size_t ws_size,
                              hipStream_t stream)
{
    const float* x0   = (const float*)d_in[0];
    const int*   ei   = (const int*)d_in[1];
    const float* wi   = (const float*)d_in[2];
    const float* bi   = (const float*)d_in[3];
    const float* wg   = (const float*)d_in[4];
    const float* asrc = (const float*)d_in[5];
    const float* adst = (const float*)d_in[6];
    const float* bg   = (const float*)d_in[7];
    const float* g1   = (const float*)d_in[8];
    const float* b1   = (const float*)d_in[9];
    const float* inw  = (const float*)d_in[10];
    const float* inb  = (const float*)d_in[11];
    const float* ow   = (const float*)d_in[12];
    const float* ob   = (const float*)d_in[13];
    const float* g2   = (const float*)d_in[14];
    const float* b2   = (const float*)d_in[15];
    const float* mw1  = (const float*)d_in[16];
    const float* mb1  = (const float*)d_in[17];
    const float* mw2  = (const float*)d_in[18];
    const float* mb2  = (const float*)d_in[19];
    const float* g3   = (const float*)d_in[20];
    const float* b3   = (const float*)d_in[21];
    const float* gf   = (const float*)d_in[22];
    const float* bf_  = (const float*)d_in[23];
    const float* wo   = (const float*)d_in[24];
    const float* bo   = (const float*)d_in[25];

    const int* srcI = ei;
    const int* dstI = ei + NEDGES;

    // ---- workspace layout ----
    const size_t NH = (size_t)NNODES * HD;           // 4,194,304
    float* ws   = (float*)d_ws;
    float* xcur = ws;                // [N,H] fp32
    float* xw   = xcur + NH;         // [N,H] fp32 (kept for layout stability)
    float* hbuf = xw + NH;           // [N,H] fp32
    float* obuf = hbuf + NH;         // [N,H] fp32
    float* qkvb = obuf + NH;         // region reused as bf16 [N,1024] (qkv|xw)
    int*   srcs    = (int*)(qkvb + 3 * NH);          // [E]
    int*   row_ptr = srcs + NEDGES;                  // [N+1]
    int*   cnt     = row_ptr + NNODES + 1;           // [N]
    int*   fill    = cnt + NNODES;                   // [N]
    float* ssrc    = (float*)(fill + NNODES);        // [N,8]
    float* sdst    = ssrc + (size_t)NNODES * NHEADS; // [N,8]
    // bf16 (short) region
    short* xq16   = (short*)qkvb;                    // [N,1024]: cols 0-767 qkv, 768-1023 xw
    short* x016   = (short*)(sdst + (size_t)NNODES * NHEADS);  // [N,128]
    short* xcur16 = x016 + (size_t)NNODES * IND;     // [N,H]
    short* b16a   = xcur16 + NH;                     // [N,H] attn-out / layer-out / final-ln
    short* hid16  = b16a + NH;                       // [N,2H]
    // bf16 weights
    short* wi_t  = hid16 + 2 * NH;                         // [256,128]
    short* wcomb = wi_t + (size_t)HD * IND;                // 4x[1024,256]
    short* ow_c  = wcomb + (size_t)LAYERS * 1024 * HD;     // 4x[256,256]
    short* mw1_t = ow_c + (size_t)LAYERS * HD * HD;        // 4x[512,256]
    short* mw2_t = mw1_t + (size_t)LAYERS * HD * 2 * HD;   // 4x[256,512]
    short* wo_t  = mw2_t + (size_t)LAYERS * 2 * HD * HD;   // [256,256]
    float* cbias = (float*)(wo_t + (size_t)HD * OUTDIM);   // 4x[1024] fp32

    const int T = 256;
    const int nNH = NNODES * NHEADS;

    // ---- weight prep ----
    cvt_kernel<<<(NNODES * IND + T - 1) / T, T, 0, stream>>>(x0, x016, NNODES * IND);
    transpose_cvt_kernel<<<dim3((IND * HD + T - 1) / T, 1), T, 0, stream>>>(wi, wi_t, IND, HD);
    build_wcomb_kernel<<<(LAYERS * 1024 * HD) / T, T, 0, stream>>>(inw, wg, wcomb);
    build_cbias_kernel<<<(LAYERS * 1024) / T, T, 0, stream>>>(inb, cbias);
    cvt_kernel<<<(LAYERS * HD * HD + T - 1) / T, T, 0, stream>>>(ow, ow_c, LAYERS * HD * HD);
    transpose_cvt_kernel<<<dim3((HD * 2 * HD + T - 1) / T, LAYERS), T, 0, stream>>>(mw1, mw1_t, HD, 2 * HD);
    transpose_cvt_kernel<<<dim3((2 * HD * HD + T - 1) / T, LAYERS), T, 0, stream>>>(mw2, mw2_t, 2 * HD, HD);
    transpose_cvt_kernel<<<dim3((HD * OUTDIM + T - 1) / T, 1), T, 0, stream>>>(wo, wo_t, HD, OUTDIM);

    // ---- CSR build ----
    hipMemsetAsync(cnt, 0, NNODES * sizeof(int), stream);
    hipMemsetAsync(fill, 0, NNODES * sizeof(int), stream);
    hist_kernel<<<(NEDGES + T - 1) / T, T, 0, stream>>>(dstI, cnt);
    scan_kernel<<<1, 256, 0, stream>>>(cnt, row_ptr);
    scatter_kernel<<<(NEDGES + T - 1) / T, T, 0, stream>>>(srcI, dstI, row_ptr, fill, srcs);

    // x = relu(x0 @ wi + bi) -> xcur fp32 + xcur16 bf16
    gemm_mfma_kernel<64><<<dim3(HD / 64, NNODES / GBM), 256, 0, stream>>>(
        x016, wi_t, bi, nullptr, xcur, xcur16, NNODES, HD, IND, 1);

    for (int i = 0; i < LAYERS; i++) {
        const float* asrc_i = asrc + (size_t)i * NHEADS * OCD;
        const float* adst_i = adst + (size_t)i * NHEADS * OCD;
        const float* bg_i   = bg + (size_t)i * HD;
        const float* g1_i   = g1 + (size_t)i * HD;
        const float* b1_i   = b1 + (size_t)i * HD;
        const float* ob_i   = ob + (size_t)i * HD;
        const float* g2_i   = g2 + (size_t)i * HD;
        const float* b2_i   = b2 + (size_t)i * HD;
        const float* mb1_i  = mb1 + (size_t)i * 2 * HD;
        const float* mb2_i  = mb2 + (size_t)i * HD;
        const float* g3_i   = g3 + (size_t)i * HD;
        const float* b3_i   = b3 + (size_t)i * HD;
        const short* wcomb_i = wcomb + (size_t)i * 1024 * HD;
        const float* cbias_i = cbias + (size_t)i * 1024;
        const short* ow_ci  = ow_c + (size_t)i * HD * HD;
        const short* mw1_ti = mw1_t + (size_t)i * HD * 2 * HD;
        const short* mw2_ti = mw2_t + (size_t)i * 2 * HD * HD;

        // ---- fused qkv+wg projection: [N,1024] = xcur16 @ [qkv|wg] ----
        gemm_mfma_kernel<128><<<dim3(1024 / 128, NNODES / GBM), 256, 0, stream>>>(
            xcur16, wcomb_i, cbias_i, nullptr, nullptr, xq16, NNODES, 1024, HD, 0);

        // ---- GAT local branch ----
        gat_scores_kernel<<<(nNH + T - 1) / T, T, 0, stream>>>(xq16 + 768, asrc_i, adst_i, ssrc, sdst);
        gat_agg_ln_kernel<<<NNODES / 4, 256, 0, stream>>>(
            row_ptr, srcs, ssrc, sdst, xq16 + 768, xcur, bg_i, g1_i, b1_i, hbuf);

        // ---- global MHA branch (all-MFMA) ----
        mha_mfma_kernel<<<dim3(NGRAPH, NHEADS), 256, 0, stream>>>(xq16, b16a);
        // fused: obuf/b16a = LN(mha@ow + ob + xcur)*g2+b2 + hbuf
        gemm_ln_kernel<<<dim3(1, NNODES / GBM), 256, 0, stream>>>(
            b16a, ow_ci, ob_i, xcur, g2_i, b2_i, hbuf, obuf, b16a, HD);

        // ---- MLP ----
        gemm_mfma_kernel<128><<<dim3(2 * HD / 128, NNODES / GBM), 256, 0, stream>>>(
            b16a, mw1_ti, mb1_i, nullptr, nullptr, hid16, NNODES, 2 * HD, HD, 1);
        // fused: xcur/xcur16 = LN(hid@mw2 + mb2 + obuf)*g3+b3
        gemm_ln_kernel<<<dim3(1, NNODES / GBM), 256, 0, stream>>>(
            hid16, mw2_ti, mb2_i, obuf, g3_i, b3_i, nullptr, xcur, xcur16, 2 * HD);
    }

    // final LN + output projection -> d_out (fp32)
    ln4_kernel<<<NNODES / 4, 256, 0, stream>>>(xcur, nullptr, gf, bf_, nullptr, nullptr, b16a);
    gemm_mfma_kernel<64><<<dim3(OUTDIM / 64, NNODES / GBM), 256, 0, stream>>>(
        b16a, wo_t, bo, nullptr, (float*)d_out, nullptr, NNODES, OUTDIM, HD, 0);
}

// Round 12
// 814.221 us; speedup vs baseline: 1.0964x; 1.0964x over previous
//
#include <hip/hip_runtime.h>
#include <hip/hip_bf16.h>

#define NNODES 16384
#define NEDGES 262144
#define IND    128
#define HD     256
#define OUTDIM 256
#define LAYERS 4
#define NHEADS 8
#define OCD    32
#define NGRAPH 64
#define NBATCH 256
#define XQSTR  1024   // combined qkv|xw row stride (shorts)

typedef __hip_bfloat16 bf16;
typedef __attribute__((ext_vector_type(8))) short bf16x8;
typedef __attribute__((ext_vector_type(4))) short s16x4;
typedef __attribute__((ext_vector_type(4))) float f32x4;

__device__ __forceinline__ short bfbits(float v) {
    bf16 h = __float2bfloat16(v);
    return *(short*)&h;
}
__device__ __forceinline__ float b2f(short s) {
    return __uint_as_float(((unsigned)(unsigned short)s) << 16);
}

// direct global->LDS DMA, 16 B/lane; lds base must be wave-uniform
__device__ __forceinline__ void gload_lds16(const short* g, short* l) {
    __builtin_amdgcn_global_load_lds(
        (const __attribute__((address_space(1))) void*)g,
        (__attribute__((address_space(3))) void*)l, 16, 0, 0);
}

// ---------------- merged prep: zeros + all weight converts/transposes ----------
// segmented 1-thread-per-item kernel; total = 4,591,616 items = 17,936 blocks
#define PREP_TOTAL (32768 + NNODES*IND + IND*HD + LAYERS*1024*HD + LAYERS*1024 \
                    + LAYERS*HD*HD + LAYERS*HD*2*HD + LAYERS*2*HD*HD + HD*OUTDIM)
__global__ void prep_kernel(const float* __restrict__ x0, const float* __restrict__ wi,
                            const float* __restrict__ inw, const float* __restrict__ wg,
                            const float* __restrict__ inb, const float* __restrict__ ow,
                            const float* __restrict__ mw1, const float* __restrict__ mw2,
                            const float* __restrict__ wo,
                            short* __restrict__ x016, short* __restrict__ wi_t,
                            short* __restrict__ wcomb, float* __restrict__ cbias,
                            short* __restrict__ ow_c, short* __restrict__ mw1_t,
                            short* __restrict__ mw2_t, short* __restrict__ wo_t,
                            int* __restrict__ cnt, int* __restrict__ fill)
{
    int i = blockIdx.x * blockDim.x + threadIdx.x;
    if (i < 32768) {                       // zero CSR counters
        if (i < NNODES) cnt[i] = 0; else fill[i - NNODES] = 0;
        return;
    }
    i -= 32768;
    if (i < NNODES * IND) { x016[i] = bfbits(x0[i]); return; }
    i -= NNODES * IND;
    if (i < IND * HD) {                    // wi [128,256] -> wi_t [256,128]
        int k = i / HD, n = i % HD;
        wi_t[n * IND + k] = bfbits(wi[i]);
        return;
    }
    i -= IND * HD;
    if (i < LAYERS * 1024 * HD) {          // wcomb rows 0..767=inw, 768..1023=wg^T
        int l = i >> 18, r = (i >> 8) & 1023, k = i & 255;
        float v = (r < 768) ? inw[(size_t)l * 768 * 256 + r * 256 + k]
                            : wg[(size_t)l * 256 * 256 + k * 256 + (r - 768)];
        wcomb[i] = bfbits(v);
        return;
    }
    i -= LAYERS * 1024 * HD;
    if (i < LAYERS * 1024) {               // cbias
        int l = i >> 10, c = i & 1023;
        cbias[i] = (c < 768) ? inb[l * 768 + c] : 0.f;
        return;
    }
    i -= LAYERS * 1024;
    if (i < LAYERS * HD * HD) { ow_c[i] = bfbits(ow[i]); return; }
    i -= LAYERS * HD * HD;
    if (i < LAYERS * HD * 2 * HD) {        // mw1 [l][256,512] -> [l][512,256]
        int l = i / (HD * 2 * HD), r = i % (HD * 2 * HD);
        int k = r / (2 * HD), n = r % (2 * HD);
        mw1_t[(size_t)l * HD * 2 * HD + n * HD + k] = bfbits(mw1[i]);
        return;
    }
    i -= LAYERS * HD * 2 * HD;
    if (i < LAYERS * 2 * HD * HD) {        // mw2 [l][512,256] -> [l][256,512]
        int l = i / (2 * HD * HD), r = i % (2 * HD * HD);
        int k = r / HD, n = r % HD;
        mw2_t[(size_t)l * 2 * HD * HD + n * 2 * HD + k] = bfbits(mw2[i]);
        return;
    }
    i -= LAYERS * 2 * HD * HD;
    if (i < HD * OUTDIM) {                 // wo [256,256] -> wo_t [256,256]^T
        int k = i / OUTDIM, n = i % OUTDIM;
        wo_t[n * HD + k] = bfbits(wo[i]);
    }
}

// ---------------- CSR build: histogram -> scan -> scatter ----------------------
__global__ void hist_kernel(const int* __restrict__ dst, int* __restrict__ cnt)
{
    int e = blockIdx.x * blockDim.x + threadIdx.x;
    if (e < NEDGES) atomicAdd(&cnt[dst[e]], 1);
}

__global__ void scan_kernel(const int* __restrict__ cnt, int* __restrict__ row_ptr)
{
    __shared__ int part[256];
    int t = threadIdx.x;
    const int PER = NNODES / 256;
    int base = t * PER;
    int s = 0;
    for (int i = 0; i < PER; i++) s += cnt[base + i];
    part[t] = s;
    __syncthreads();
    for (int off = 1; off < 256; off <<= 1) {
        int v = (t >= off) ? part[t - off] : 0;
        __syncthreads();
        part[t] += v;
        __syncthreads();
    }
    int run = (t == 0) ? 0 : part[t - 1];
    for (int i = 0; i < PER; i++) { row_ptr[base + i] = run; run += cnt[base + i]; }
    if (t == 255) row_ptr[NNODES] = run;
}

__global__ void scatter_kernel(const int* __restrict__ src, const int* __restrict__ dst,
                               const int* __restrict__ row_ptr, int* __restrict__ fill,
                               int* __restrict__ srcs)
{
    int e = blockIdx.x * blockDim.x + threadIdx.x;
    if (e >= NEDGES) return;
    int d = dst[e];
    int pos = row_ptr[d] + atomicAdd(&fill[d], 1);
    srcs[pos] = src[e];
}

// ---------------- GAT per-node attention scores (bf16 xw, stride XQSTR) --------
__global__ void gat_scores_kernel(const short* __restrict__ xw16,
                                  const float* __restrict__ asrc, const float* __restrict__ adst,
                                  float* __restrict__ ssrc, float* __restrict__ sdst)
{
    int i = blockIdx.x * blockDim.x + threadIdx.x;   // n*NHEADS + h
    if (i >= NNODES * NHEADS) return;
    int n = i >> 3, h = i & 7;
    const bf16x8* xr = (const bf16x8*)(xw16 + (size_t)n * XQSTR + h * OCD);
    float s1 = 0.f, s2 = 0.f;
#pragma unroll
    for (int g = 0; g < 4; g++) {
        bf16x8 v8 = xr[g];
#pragma unroll
        for (int j = 0; j < 8; j++) {
            float v = b2f(v8[j]);
            int d = g * 8 + j;
            s1 += v * asrc[h * OCD + d];
            s2 += v * adst[h * OCD + d];
        }
    }
    ssrc[i] = s1;
    sdst[i] = s2;
}

// ---------------- fused GAT softmax + aggregation + LayerNorm ------------------
// Wave-per-node: 4 channels/lane, 8 B row-gathers, no barriers; shuffle LN.
__global__ __launch_bounds__(256)
void gat_agg_ln_kernel(const int* __restrict__ row_ptr, const int* __restrict__ srcs,
                       const float* __restrict__ ssrc, const float* __restrict__ sdst,
                       const short* __restrict__ xw16, const float* __restrict__ xcur,
                       const float* __restrict__ colbias, const float* __restrict__ gamma,
                       const float* __restrict__ beta, float* __restrict__ out)
{
    int wave = threadIdx.x >> 6, lane = threadIdx.x & 63;
    int n = blockIdx.x * 4 + wave;
    int c0 = lane << 2;            // 4 channels per lane
    int h = c0 >> 5;               // head of all 4 channels
    int start = row_ptr[n];
    int deg = row_ptr[n + 1] - start;
    float sd = sdst[n * NHEADS + h];

    float ax = 0.f, ay = 0.f, az = 0.f, aw = 0.f, l = 0.f;
    int j = 0;
    for (; j + 4 <= deg; j += 4) {
        int e0 = srcs[start + j + 0], e1 = srcs[start + j + 1];
        int e2 = srcs[start + j + 2], e3 = srcs[start + j + 3];
        s16x4 r0 = *(const s16x4*)&xw16[(size_t)e0 * XQSTR + c0];
        s16x4 r1 = *(const s16x4*)&xw16[(size_t)e1 * XQSTR + c0];
        s16x4 r2 = *(const s16x4*)&xw16[(size_t)e2 * XQSTR + c0];
        s16x4 r3 = *(const s16x4*)&xw16[(size_t)e3 * XQSTR + c0];
        float a0 = ssrc[e0 * NHEADS + h] + sd; a0 = a0 > 0.f ? a0 : 0.2f * a0;
        float a1 = ssrc[e1 * NHEADS + h] + sd; a1 = a1 > 0.f ? a1 : 0.2f * a1;
        float a2 = ssrc[e2 * NHEADS + h] + sd; a2 = a2 > 0.f ? a2 : 0.2f * a2;
        float a3 = ssrc[e3 * NHEADS + h] + sd; a3 = a3 > 0.f ? a3 : 0.2f * a3;
        float p0 = __expf(a0), p1 = __expf(a1), p2 = __expf(a2), p3 = __expf(a3);
        l += (p0 + p1) + (p2 + p3);
        ax += p0 * b2f(r0[0]) + p1 * b2f(r1[0]) + p2 * b2f(r2[0]) + p3 * b2f(r3[0]);
        ay += p0 * b2f(r0[1]) + p1 * b2f(r1[1]) + p2 * b2f(r2[1]) + p3 * b2f(r3[1]);
        az += p0 * b2f(r0[2]) + p1 * b2f(r1[2]) + p2 * b2f(r2[2]) + p3 * b2f(r3[2]);
        aw += p0 * b2f(r0[3]) + p1 * b2f(r1[3]) + p2 * b2f(r2[3]) + p3 * b2f(r3[3]);
    }
    for (; j < deg; j++) {
        int e0 = srcs[start + j];
        s16x4 r0 = *(const s16x4*)&xw16[(size_t)e0 * XQSTR + c0];
        float a0 = ssrc[e0 * NHEADS + h] + sd; a0 = a0 > 0.f ? a0 : 0.2f * a0;
        float p0 = __expf(a0);
        l += p0;
        ax += p0 * b2f(r0[0]); ay += p0 * b2f(r0[1]);
        az += p0 * b2f(r0[2]); aw += p0 * b2f(r0[3]);
    }
    float invl = deg ? 1.f / l : 0.f;
    size_t base = (size_t)n * HD + c0;
    float4 x4 = *(const float4*)&xcur[base];
    float4 cb = *(const float4*)&colbias[c0];
    float4 v;
    v.x = ax * invl + x4.x + cb.x;
    v.y = ay * invl + x4.y + cb.y;
    v.z = az * invl + x4.z + cb.z;
    v.w = aw * invl + x4.w + cb.w;
    float s = v.x + v.y + v.z + v.w;
    float q = v.x * v.x + v.y * v.y + v.z * v.z + v.w * v.w;
#pragma unroll
    for (int off = 1; off < 64; off <<= 1) {
        s += __shfl_xor(s, off);
        q += __shfl_xor(q, off);
    }
    float mean = s * (1.f / HD);
    float var  = fmaxf(q * (1.f / HD) - mean * mean, 0.f);
    float inv  = rsqrtf(var + 1e-5f);
    float4 g  = *(const float4*)&gamma[c0];
    float4 bt = *(const float4*)&beta[c0];
    float4 y;
    y.x = (v.x - mean) * inv * g.x + bt.x;
    y.y = (v.y - mean) * inv * g.y + bt.y;
    y.z = (v.z - mean) * inv * g.z + bt.z;
    y.w = (v.w - mean) * inv * g.w + bt.w;
    *(float4*)&out[base] = y;
}

// ---------------- bf16 MFMA GEMM: C = A @ B^T (+bias)(+resid)(relu) ------------
// SWAPPED-operand mfma: mfma(bF, aF) puts lane l16 on the ROW and quad*4+r on
// 4 CONSECUTIVE COLUMNS -> float4 / s16x4 vectorized epilogue.
#define GBM 128
#define GBK 32

template<int TN>
__global__ __launch_bounds__(256)
void gemm_mfma_kernel(const short* __restrict__ A16, const short* __restrict__ B16,
                      const float* __restrict__ bias, const float* __restrict__ resid,
                      float* __restrict__ Cf, short* __restrict__ C16,
                      int M, int Nc, int K, int relu)
{
    constexpr int NTF = TN / 32;          // n-frags per wave
    __shared__ short As[GBM * GBK];       // 8 KB
    __shared__ short Bs[TN * GBK];        // 4 or 8 KB
    int tid = threadIdx.x;
    int wid = tid >> 6, lane = tid & 63;
    int quad = lane >> 4, l16 = lane & 15;
    int wm = wid >> 1, wn = wid & 1;
    int rowBase = blockIdx.y * GBM;
    int colBase = blockIdx.x * TN;

    f32x4 acc[4][NTF];
#pragma unroll
    for (int mt = 0; mt < 4; mt++)
#pragma unroll
        for (int nt = 0; nt < NTF; nt++) acc[mt][nt] = (f32x4)(0.f);

    int ar  = tid >> 2;          // 0..63
    int akq = (tid & 3) * 8;     // 0,8,16,24 (shorts)

    const short* Ag0 = &A16[(size_t)(rowBase + ar) * K + akq];
    const short* Ag1 = &A16[(size_t)(rowBase + ar + 64) * K + akq];
    const short* Bg0 = &B16[(size_t)(colBase + ar) * K + akq];
    const short* Bg1 = (TN == 128) ? &B16[(size_t)(colBase + ar + 64) * K + akq] : nullptr;
    short* AsW0 = As + wid * 512;                 // wave-uniform LDS bases (shorts)
    short* AsW1 = As + 64 * GBK + wid * 512;
    short* BsW0 = Bs + wid * 512;
    short* BsW1 = Bs + 64 * GBK + wid * 512;

    for (int k0 = 0; k0 < K; k0 += GBK) {
        gload_lds16(Ag0 + k0, AsW0);
        gload_lds16(Ag1 + k0, AsW1);
        gload_lds16(Bg0 + k0, BsW0);
        if (TN == 128) gload_lds16(Bg1 + k0, BsW1);
        __syncthreads();
        bf16x8 aF[4], bF[NTF];
#pragma unroll
        for (int mt = 0; mt < 4; mt++)
            aF[mt] = *(bf16x8*)&As[(wm * 64 + mt * 16 + l16) * GBK + quad * 8];
#pragma unroll
        for (int nt = 0; nt < NTF; nt++)
            bF[nt] = *(bf16x8*)&Bs[(wn * (TN / 2) + nt * 16 + l16) * GBK + quad * 8];
#pragma unroll
        for (int mt = 0; mt < 4; mt++)
#pragma unroll
            for (int nt = 0; nt < NTF; nt++)
                acc[mt][nt] = __builtin_amdgcn_mfma_f32_16x16x32_bf16(
                    bF[nt], aF[mt], acc[mt][nt], 0, 0, 0);   // swapped operands
        __syncthreads();
    }

    // epilogue: row = ...+l16, cols = ...+quad*4+{0..3} (contiguous)
#pragma unroll
    for (int mt = 0; mt < 4; mt++) {
        int row = rowBase + wm * 64 + mt * 16 + l16;
#pragma unroll
        for (int nt = 0; nt < NTF; nt++) {
            int col0 = colBase + wn * (TN / 2) + nt * 16 + quad * 4;
            f32x4 v = acc[mt][nt];
            if (bias) {
                float4 b4 = *(const float4*)&bias[col0];
                v[0] += b4.x; v[1] += b4.y; v[2] += b4.z; v[3] += b4.w;
            }
            if (resid) {
                float4 r4 = *(const float4*)&resid[(size_t)row * Nc + col0];
                v[0] += r4.x; v[1] += r4.y; v[2] += r4.z; v[3] += r4.w;
            }
            if (relu) {
                v[0] = fmaxf(v[0], 0.f); v[1] = fmaxf(v[1], 0.f);
                v[2] = fmaxf(v[2], 0.f); v[3] = fmaxf(v[3], 0.f);
            }
            if (Cf) {
                float4 o; o.x = v[0]; o.y = v[1]; o.z = v[2]; o.w = v[3];
                *(float4*)&Cf[(size_t)row * Nc + col0] = o;
            }
            if (C16) {
                s16x4 o;
                o[0] = bfbits(v[0]); o[1] = bfbits(v[1]);
                o[2] = bfbits(v[2]); o[3] = bfbits(v[3]);
                *(s16x4*)&C16[(size_t)row * Nc + col0] = o;
            }
        }
    }
}

// ---------------- fused GEMM + residual + LayerNorm (+postadd) -----------------
// 64-row x 256-col tile (256 blocks -> full device). Wave wid owns rows
// wid*16..+15; each row's 256 cols live in ONE wave -> LN reduce is 2 shuffles.
__global__ __launch_bounds__(256)
void gemm_ln_kernel(const short* __restrict__ A16, const short* __restrict__ B16,
                    const float* __restrict__ bias, const float* __restrict__ resid,
                    const float* __restrict__ gamma, const float* __restrict__ beta,
                    const float* __restrict__ postadd,
                    float* __restrict__ outf, short* __restrict__ out16, int K)
{
    __shared__ short As[64 * GBK];        // 4 KB
    __shared__ short Bs[256 * GBK];       // 16 KB
    int tid = threadIdx.x;
    int wid = tid >> 6, lane = tid & 63;
    int quad = lane >> 4, l16 = lane & 15;
    int rowBase = blockIdx.y * 64;

    f32x4 acc[16];
#pragma unroll
    for (int nt = 0; nt < 16; nt++) acc[nt] = (f32x4)(0.f);

    int ar  = tid >> 2;
    int akq = (tid & 3) * 8;

    const short* Ag  = &A16[(size_t)(rowBase + ar) * K + akq];
    const short* Bg0 = &B16[(size_t)(ar) * K + akq];
    const short* Bg1 = &B16[(size_t)(ar + 64) * K + akq];
    const short* Bg2 = &B16[(size_t)(ar + 128) * K + akq];
    const short* Bg3 = &B16[(size_t)(ar + 192) * K + akq];
    short* AsW  = As + wid * 512;
    short* BsW0 = Bs + wid * 512;
    short* BsW1 = Bs + 64 * GBK + wid * 512;
    short* BsW2 = Bs + 128 * GBK + wid * 512;
    short* BsW3 = Bs + 192 * GBK + wid * 512;

    for (int k0 = 0; k0 < K; k0 += GBK) {
        gload_lds16(Ag + k0, AsW);
        gload_lds16(Bg0 + k0, BsW0);
        gload_lds16(Bg1 + k0, BsW1);
        gload_lds16(Bg2 + k0, BsW2);
        gload_lds16(Bg3 + k0, BsW3);
        __syncthreads();
        bf16x8 aF = *(bf16x8*)&As[(wid * 16 + l16) * GBK + quad * 8];
#pragma unroll
        for (int nt = 0; nt < 16; nt++) {
            bf16x8 bF = *(bf16x8*)&Bs[(nt * 16 + l16) * GBK + quad * 8];
            acc[nt] = __builtin_amdgcn_mfma_f32_16x16x32_bf16(bF, aF, acc[nt], 0, 0, 0);
        }
        __syncthreads();
    }

    int row = rowBase + wid * 16 + l16;
    float s = 0.f, q = 0.f;
#pragma unroll
    for (int nt = 0; nt < 16; nt++) {
        int col0 = nt * 16 + quad * 4;
        f32x4 v = acc[nt];
        float4 b4 = *(const float4*)&bias[col0];
        float4 r4 = *(const float4*)&resid[(size_t)row * HD + col0];
        v[0] += b4.x + r4.x; v[1] += b4.y + r4.y;
        v[2] += b4.z + r4.z; v[3] += b4.w + r4.w;
        acc[nt] = v;
        s += (v[0] + v[1]) + (v[2] + v[3]);
        q += (v[0] * v[0] + v[1] * v[1]) + (v[2] * v[2] + v[3] * v[3]);
    }
    // reduce over the 4 quads holding this row (lanes l16, +16, +32, +48)
    s += __shfl_xor(s, 16); s += __shfl_xor(s, 32);
    q += __shfl_xor(q, 16); q += __shfl_xor(q, 32);
    float mean = s * (1.f / HD);
    float var  = fmaxf(q * (1.f / HD) - mean * mean, 0.f);
    float inv  = rsqrtf(var + 1e-5f);
#pragma unroll
    for (int nt = 0; nt < 16; nt++) {
        int col0 = nt * 16 + quad * 4;
        f32x4 v = acc[nt];
        float4 g4 = *(const float4*)&gamma[col0];
        float4 bt = *(const float4*)&beta[col0];
        float4 y;
        y.x = (v[0] - mean) * inv * g4.x + bt.x;
        y.y = (v[1] - mean) * inv * g4.y + bt.y;
        y.z = (v[2] - mean) * inv * g4.z + bt.z;
        y.w = (v[3] - mean) * inv * g4.w + bt.w;
        if (postadd) {
            float4 p4 = *(const float4*)&postadd[(size_t)row * HD + col0];
            y.x += p4.x; y.y += p4.y; y.z += p4.z; y.w += p4.w;
        }
        *(float4*)&outf[(size_t)row * HD + col0] = y;
        s16x4 o;
        o[0] = bfbits(y.x); o[1] = bfbits(y.y); o[2] = bfbits(y.z); o[3] = bfbits(y.w);
        *(s16x4*)&out16[(size_t)row * HD + col0] = o;
    }
}

// ---------------- LayerNorm: wave-per-row, float4, shuffle-only ----------------
__global__ __launch_bounds__(256)
void ln4_kernel(const float* __restrict__ in, const float* __restrict__ res,
                const float* __restrict__ gamma, const float* __restrict__ beta,
                const float* __restrict__ postadd,
                float* __restrict__ outf, short* __restrict__ out16)
{
    int wave = threadIdx.x >> 6, lane = threadIdx.x & 63;
    int row = blockIdx.x * 4 + wave;
    size_t base = (size_t)row * HD + lane * 4;
    float4 v = *(const float4*)&in[base];
    if (res) {
        float4 r = *(const float4*)&res[base];
        v.x += r.x; v.y += r.y; v.z += r.z; v.w += r.w;
    }
    float s = v.x + v.y + v.z + v.w;
    float q = v.x * v.x + v.y * v.y + v.z * v.z + v.w * v.w;
#pragma unroll
    for (int off = 1; off < 64; off <<= 1) {
        s += __shfl_xor(s, off);
        q += __shfl_xor(q, off);
    }
    float mean = s * (1.f / HD);
    float var  = fmaxf(q * (1.f / HD) - mean * mean, 0.f);
    float inv  = rsqrtf(var + 1e-5f);
    float4 g  = *(const float4*)&gamma[lane * 4];
    float4 bt = *(const float4*)&beta[lane * 4];
    float4 y;
    y.x = (v.x - mean) * inv * g.x + bt.x;
    y.y = (v.y - mean) * inv * g.y + bt.y;
    y.z = (v.z - mean) * inv * g.z + bt.z;
    y.w = (v.w - mean) * inv * g.w + bt.w;
    if (postadd) {
        float4 p = *(const float4*)&postadd[base];
        y.x += p.x; y.y += p.y; y.z += p.z; y.w += p.w;
    }
    if (outf) *(float4*)&outf[base] = y;
    if (out16) {
        s16x4 o;
        o[0] = bfbits(y.x); o[1] = bfbits(y.y); o[2] = bfbits(y.z); o[3] = bfbits(y.w);
        *(s16x4*)&out16[base] = o;
    }
}

// ---------------- MFMA per-graph MHA (qkv stride XQSTR) ------------------------
#define PSTR 72                       // P/VT row stride in shorts: 2-way bank alias only
__global__ __launch_bounds__(256)
void mha_mfma_kernel(const short* __restrict__ qkv16, short* __restrict__ o16)
{
    __shared__ short smem[4 * 64 * PSTR + 32 * PSTR];   // P (4w x 64q x 64k) + V^T (32d x 64k)
    short* VT = smem + 4 * 64 * PSTR;

    int b = blockIdx.x, h = blockIdx.y;
    int tid = threadIdx.x;
    int wid = tid >> 6, lane = tid & 63;
    int quad = lane >> 4, l16 = lane & 15;
    int base = b * NBATCH;
    int qrow0 = wid * 64;
    short* Pme = smem + wid * 64 * PSTR;

    const float scale2 = 0.17677669529663687f * 1.4426950408889634f; // 1/sqrt(32)*log2(e)

    bf16x8 qA[4];
#pragma unroll
    for (int mt = 0; mt < 4; mt++)
        qA[mt] = *(const bf16x8*)&qkv16[(size_t)(base + qrow0 + mt * 16 + l16) * XQSTR + h * 32 + quad * 8];

    f32x4 accO[4][2];
#pragma unroll
    for (int mt = 0; mt < 4; mt++)
#pragma unroll
        for (int dt = 0; dt < 2; dt++) accO[mt][dt] = (f32x4)(0.f);
    float lsum[4][4];
#pragma unroll
    for (int mt = 0; mt < 4; mt++)
#pragma unroll
        for (int r = 0; r < 4; r++) lsum[mt][r] = 0.f;

    for (int c = 0; c < 4; c++) {                  // 4 key-chunks of 64
        __syncthreads();
        {
            int key = tid >> 2, dq = (tid & 3) * 8;
            bf16x8 v = *(const bf16x8*)&qkv16[(size_t)(base + c * 64 + key) * XQSTR + 512 + h * 32 + dq];
#pragma unroll
            for (int j = 0; j < 8; j++) VT[(dq + j) * PSTR + key] = v[j];
        }
        __syncthreads();
        bf16x8 kB[4];
#pragma unroll
        for (int kt = 0; kt < 4; kt++)
            kB[kt] = *(const bf16x8*)&qkv16[(size_t)(base + c * 64 + kt * 16 + l16) * XQSTR + 256 + h * 32 + quad * 8];
#pragma unroll
        for (int mt = 0; mt < 4; mt++) {
#pragma unroll
            for (int kt = 0; kt < 4; kt++) {
                f32x4 s = __builtin_amdgcn_mfma_f32_16x16x32_bf16(qA[mt], kB[kt], (f32x4)(0.f), 0, 0, 0);
#pragma unroll
                for (int r = 0; r < 4; r++) {
                    float p = exp2f(s[r] * scale2);
                    lsum[mt][r] += p;
                    Pme[(mt * 16 + quad * 4 + r) * PSTR + kt * 16 + l16] = bfbits(p);
                }
            }
        }
        __syncthreads();
#pragma unroll
        for (int mt = 0; mt < 4; mt++) {
#pragma unroll
            for (int ks = 0; ks < 2; ks++) {
                bf16x8 pA = *(bf16x8*)&Pme[(mt * 16 + l16) * PSTR + ks * 32 + quad * 8];
#pragma unroll
                for (int dt = 0; dt < 2; dt++) {
                    bf16x8 vB = *(bf16x8*)&VT[(dt * 16 + l16) * PSTR + ks * 32 + quad * 8];
                    accO[mt][dt] = __builtin_amdgcn_mfma_f32_16x16x32_bf16(pA, vB, accO[mt][dt], 0, 0, 0);
                }
            }
        }
    }
#pragma unroll
    for (int mt = 0; mt < 4; mt++)
#pragma unroll
        for (int r = 0; r < 4; r++) {
            float v = lsum[mt][r];
            v += __shfl_xor(v, 1);
            v += __shfl_xor(v, 2);
            v += __shfl_xor(v, 4);
            v += __shfl_xor(v, 8);
            lsum[mt][r] = v;
        }
#pragma unroll
    for (int mt = 0; mt < 4; mt++)
#pragma unroll
        for (int dt = 0; dt < 2; dt++)
#pragma unroll
            for (int r = 0; r < 4; r++) {
                int row = base + qrow0 + mt * 16 + quad * 4 + r;
                int col = h * 32 + dt * 16 + l16;
                o16[(size_t)row * HD + col] = bfbits(accO[mt][dt][r] / lsum[mt][r]);
            }
}

// ------------------------------------------------------------------------------
extern "C" void kernel_launch(void* const* d_in, const int* in_sizes, int n_in,
                              void* d_out, int out_size, void* d_ws, size_t ws_size,
                              hipStream_t stream)
{
    const float* x0   = (const float*)d_in[0];
    const int*   ei   = (const int*)d_in[1];
    const float* wi   = (const float*)d_in[2];
    const float* bi   = (const float*)d_in[3];
    const float* wg   = (const float*)d_in[4];
    const float* asrc = (const float*)d_in[5];
    const float* adst = (const float*)d_in[6];
    const float* bg   = (const float*)d_in[7];
    const float* g1   = (const float*)d_in[8];
    const float* b1   = (const float*)d_in[9];
    const float* inw  = (const float*)d_in[10];
    const float* inb  = (const float*)d_in[11];
    const float* ow   = (const float*)d_in[12];
    const float* ob   = (const float*)d_in[13];
    const float* g2   = (const float*)d_in[14];
    const float* b2   = (const float*)d_in[15];
    const float* mw1  = (const float*)d_in[16];
    const float* mb1  = (const float*)d_in[17];
    const float* mw2  = (const float*)d_in[18];
    const float* mb2  = (const float*)d_in[19];
    const float* g3   = (const float*)d_in[20];
    const float* b3   = (const float*)d_in[21];
    const float* gf   = (const float*)d_in[22];
    const float* bf_  = (const float*)d_in[23];
    const float* wo   = (const float*)d_in[24];
    const float* bo   = (const float*)d_in[25];

    const int* srcI = ei;
    const int* dstI = ei + NEDGES;

    // ---- workspace layout ----
    const size_t NH = (size_t)NNODES * HD;           // 4,194,304
    float* ws   = (float*)d_ws;
    float* xcur = ws;                // [N,H] fp32
    float* xw   = xcur + NH;         // [N,H] fp32 (layout stability)
    float* hbuf = xw + NH;           // [N,H] fp32
    float* obuf = hbuf + NH;         // [N,H] fp32
    float* qkvb = obuf + NH;         // region reused as bf16 [N,1024] (qkv|xw)
    int*   srcs    = (int*)(qkvb + 3 * NH);          // [E]
    int*   row_ptr = srcs + NEDGES;                  // [N+1]
    int*   cnt     = row_ptr + NNODES + 1;           // [N]
    int*   fill    = cnt + NNODES;                   // [N]
    float* ssrc    = (float*)(fill + NNODES);        // [N,8]
    float* sdst    = ssrc + (size_t)NNODES * NHEADS; // [N,8]
    // bf16 (short) region
    short* xq16   = (short*)qkvb;                    // [N,1024]: cols 0-767 qkv, 768-1023 xw
    short* x016   = (short*)(sdst + (size_t)NNODES * NHEADS);  // [N,128]
    short* xcur16 = x016 + (size_t)NNODES * IND;     // [N,H]
    short* b16a   = xcur16 + NH;                     // [N,H] attn-out / layer-out / final-ln
    short* hid16  = b16a + NH;                       // [N,2H]
    // bf16 weights
    short* wi_t  = hid16 + 2 * NH;                         // [256,128]
    short* wcomb = wi_t + (size_t)HD * IND;                // 4x[1024,256]
    short* ow_c  = wcomb + (size_t)LAYERS * 1024 * HD;     // 4x[256,256]
    short* mw1_t = ow_c + (size_t)LAYERS * HD * HD;        // 4x[512,256]
    short* mw2_t = mw1_t + (size_t)LAYERS * HD * 2 * HD;   // 4x[256,512]
    short* wo_t  = mw2_t + (size_t)LAYERS * 2 * HD * HD;   // [256,256]
    float* cbias = (float*)(wo_t + (size_t)HD * OUTDIM);   // 4x[1024] fp32

    const int T = 256;
    const int nNH = NNODES * NHEADS;

    // ---- merged prep (zeros + all weight converts) ----
    prep_kernel<<<(PREP_TOTAL + T - 1) / T, T, 0, stream>>>(
        x0, wi, inw, wg, inb, ow, mw1, mw2, wo,
        x016, wi_t, wcomb, cbias, ow_c, mw1_t, mw2_t, wo_t, cnt, fill);

    // ---- CSR build ----
    hist_kernel<<<(NEDGES + T - 1) / T, T, 0, stream>>>(dstI, cnt);
    scan_kernel<<<1, 256, 0, stream>>>(cnt, row_ptr);
    scatter_kernel<<<(NEDGES + T - 1) / T, T, 0, stream>>>(srcI, dstI, row_ptr, fill, srcs);

    // x = relu(x0 @ wi + bi) -> xcur fp32 + xcur16 bf16
    gemm_mfma_kernel<64><<<dim3(HD / 64, NNODES / GBM), 256, 0, stream>>>(
        x016, wi_t, bi, nullptr, xcur, xcur16, NNODES, HD, IND, 1);

    for (int i = 0; i < LAYERS; i++) {
        const float* asrc_i = asrc + (size_t)i * NHEADS * OCD;
        const float* adst_i = adst + (size_t)i * NHEADS * OCD;
        const float* bg_i   = bg + (size_t)i * HD;
        const float* g1_i   = g1 + (size_t)i * HD;
        const float* b1_i   = b1 + (size_t)i * HD;
        const float* ob_i   = ob + (size_t)i * HD;
        const float* g2_i   = g2 + (size_t)i * HD;
        const float* b2_i   = b2 + (size_t)i * HD;
        const float* mb1_i  = mb1 + (size_t)i * 2 * HD;
        const float* mb2_i  = mb2 + (size_t)i * HD;
        const float* g3_i   = g3 + (size_t)i * HD;
        const float* b3_i   = b3 + (size_t)i * HD;
        const short* wcomb_i = wcomb + (size_t)i * 1024 * HD;
        const float* cbias_i = cbias + (size_t)i * 1024;
        const short* ow_ci  = ow_c + (size_t)i * HD * HD;
        const short* mw1_ti = mw1_t + (size_t)i * HD * 2 * HD;
        const short* mw2_ti = mw2_t + (size_t)i * 2 * HD * HD;

        // ---- fused qkv+wg projection: [N,1024] = xcur16 @ [qkv|wg] ----
        gemm_mfma_kernel<128><<<dim3(1024 / 128, NNODES / GBM), 256, 0, stream>>>(
            xcur16, wcomb_i, cbias_i, nullptr, nullptr, xq16, NNODES, 1024, HD, 0);

        // ---- GAT local branch ----
        gat_scores_kernel<<<(nNH + T - 1) / T, T, 0, stream>>>(xq16 + 768, asrc_i, adst_i, ssrc, sdst);
        gat_agg_ln_kernel<<<NNODES / 4, 256, 0, stream>>>(
            row_ptr, srcs, ssrc, sdst, xq16 + 768, xcur, bg_i, g1_i, b1_i, hbuf);

        // ---- global MHA branch (all-MFMA) ----
        mha_mfma_kernel<<<dim3(NGRAPH, NHEADS), 256, 0, stream>>>(xq16, b16a);
        // fused: obuf/b16a = LN(mha@ow + ob + xcur)*g2+b2 + hbuf
        gemm_ln_kernel<<<dim3(1, NNODES / 64), 256, 0, stream>>>(
            b16a, ow_ci, ob_i, xcur, g2_i, b2_i, hbuf, obuf, b16a, HD);

        // ---- MLP ----
        gemm_mfma_kernel<128><<<dim3(2 * HD / 128, NNODES / GBM), 256, 0, stream>>>(
            b16a, mw1_ti, mb1_i, nullptr, nullptr, hid16, NNODES, 2 * HD, HD, 1);
        // fused: xcur/xcur16 = LN(hid@mw2 + mb2 + obuf)*g3+b3
        gemm_ln_kernel<<<dim3(1, NNODES / 64), 256, 0, stream>>>(
            hid16, mw2_ti, mb2_i, obuf, g3_i, b3_i, nullptr, xcur, xcur16, 2 * HD);
    }

    // final LN + output projection -> d_out (fp32)
    ln4_kernel<<<NNODES / 4, 256, 0, stream>>>(xcur, nullptr, gf, bf_, nullptr, nullptr, b16a);
    gemm_mfma_kernel<64><<<dim3(OUTDIM / 64, NNODES / GBM), 256, 0, stream>>>(
        b16a, wo_t, bo, nullptr, (float*)d_out, nullptr, NNODES, OUTDIM, HD, 0);
}